// Round 1
// baseline (334.648 us; speedup 1.0000x reference)
//
#include <hip/hip_runtime.h>
#include <hip/hip_bf16.h>
#include <stdint.h>

using bf16 = __hip_bfloat16;
typedef __attribute__((ext_vector_type(8))) short bf16x8;
typedef __attribute__((ext_vector_type(4))) float f32x4;

#define BATCHN 512

// ---------------- async global->LDS 16B helper ----------------
__device__ __forceinline__ void gload_lds16(const void* g, void* l) {
  __builtin_amdgcn_global_load_lds(
      (const __attribute__((address_space(1))) uint32_t*)g,
      (__attribute__((address_space(3))) uint32_t*)l, 16, 0, 0);
}

// ---------------- gating + leaf probs ----------------
// grid 512 x 64 threads. lp[b][leaf] fp32.
__global__ void gate_kernel(const float* __restrict__ x, const float* __restrict__ gw,
                            const float* __restrict__ gb, float* __restrict__ lp) {
  __shared__ float xs[128];
  __shared__ float gs[32];
  const int b = blockIdx.x;
  const int t = threadIdx.x; // 0..63
  xs[t] = x[b*128 + t];
  xs[t + 64] = x[b*128 + 64 + t];
  __syncthreads();
  if (t < 31) {
    float acc = gb[t];
    #pragma unroll 8
    for (int k = 0; k < 128; ++k) acc += xs[k] * gw[k*31 + t];
    gs[t] = 1.f / (1.f + __expf(-acc));
  }
  __syncthreads();
  if (t < 32) {
    float prob = 1.f;
    #pragma unroll
    for (int d = 1; d <= 5; ++d) {
      int i = t >> (6 - d);
      int node = (1 << (d - 1)) - 1 + i;
      float gv = gs[node];
      prob *= ((t >> (5 - d)) & 1) ? (1.f - gv) : gv;
    }
    lp[b*32 + t] = prob;
  }
}

// ---------------- mixture: out0 = lp @ z.T, written NHWC bf16 into x1 halo ----------------
// grid (64 spatial, 8 b-chunks) x 256 threads.
__global__ void mixture_kernel(const float* __restrict__ z, const float* __restrict__ lp,
                               bf16* __restrict__ x1) {
  __shared__ float lps[64 * 32];
  const int s = blockIdx.x;          // h*8+w
  const int h = s >> 3, w = s & 7;
  const int b0 = blockIdx.y * 64;
  const int t = threadIdx.x;
  const int c = t & 127;
  const int half = t >> 7;
  float4 zr[8];
  const float4* zp = (const float4*)(z + (size_t)(c * 64 + s) * 32);
  #pragma unroll
  for (int i = 0; i < 8; ++i) zr[i] = zp[i];
  #pragma unroll
  for (int i = 0; i < 8; ++i) lps[t + 256 * i] = lp[b0 * 32 + t + 256 * i];
  __syncthreads();
  for (int bs = 0; bs < 32; ++bs) {
    int bl = half * 32 + bs;
    const float4* lr = (const float4*)(lps + bl * 32);
    float acc = 0.f;
    #pragma unroll
    for (int i = 0; i < 8; ++i) {
      float4 l4 = lr[i];
      acc += zr[i].x * l4.x + zr[i].y * l4.y + zr[i].z * l4.z + zr[i].w * l4.w;
    }
    int b = b0 + bl;
    x1[((size_t)(b * 10 + h + 1) * 10 + (w + 1)) * 128 + c] = __float2bfloat16(acc);
  }
}

// ---------------- zero the 1-px halo border of [512][H+2][W+2][C] bf16 ----------------
__global__ void zero_halo(bf16* __restrict__ buf, int H, int W, int C) {
  int idx = blockIdx.x * 256 + threadIdx.x;
  int nvec = C >> 3;
  int P = 2 * (W + 2) + 2 * H;
  int total = BATCHN * P * nvec;
  if (idx >= total) return;
  int cv = idx % nvec;
  int p = (idx / nvec) % P;
  int b = idx / (nvec * P);
  int row, col;
  if (p < W + 2) { row = 0; col = p; }
  else if (p < 2 * (W + 2)) { row = H + 1; col = p - (W + 2); }
  else { int q = p - 2 * (W + 2); row = 1 + (q >> 1); col = (q & 1) ? (W + 1) : 0; }
  float4 z4 = {0.f, 0.f, 0.f, 0.f};
  *(float4*)(buf + ((size_t)(b * (H + 2) + row) * (W + 2) + col) * C + cv * 8) = z4;
}

// ---------------- weight prep: w[ic][ocr][4][4] fp32 -> wt[parity][ocp][tap][ic] bf16 ----------------
// parity p=(py,px); tap=(dy,dx); dy=0 -> input offset 0, dy=1 -> offset (py? +1 : -1).
// ky table: py=0:{1,3}  py=1:{2,0}   (same for x)
__global__ void wprep_kernel(const float* __restrict__ w, bf16* __restrict__ wt,
                             int IC, int OCr, int OCp) {
  int idx = blockIdx.x * 256 + threadIdx.x;
  int total = 4 * OCp * 4 * IC;
  if (idx >= total) return;
  int ic = idx % IC;
  int tap = (idx / IC) & 3;
  int oc = (idx / (4 * IC)) % OCp;
  int p = idx / (4 * IC * OCp);
  int dy = tap >> 1, dx = tap & 1;
  int py = p >> 1, px = p & 1;
  const int ktab[2][2] = {{1, 3}, {2, 0}};
  int ky = ktab[py][dy], kx = ktab[px][dx];
  float v = 0.f;
  if (oc < OCr) v = w[((ic * OCr + oc) * 4 + ky) * 4 + kx];
  wt[idx] = __float2bfloat16(v);
}

// ---------------- transposed-conv as per-parity implicit GEMM (bf16 MFMA) ----------------
// xin:  [512][IH+2][IW+2][IC] bf16 (zero halo)
// wt:   [4][OCp][4*IC] bf16
// out:  either xout [512][2IH+2][2IW+2][OCp] bf16 (+relu), or fout [512][3][64][64] fp32
template<int IC, int OCp, int OCr, int IH, int IW, int BM, int BN, int WM, int WN, bool RELU, bool FINAL>
__global__ __launch_bounds__(256, 2)
void convt_mfma(const bf16* __restrict__ xin, const bf16* __restrict__ wt,
                const float* __restrict__ bias, bf16* __restrict__ xout,
                float* __restrict__ fout) {
  constexpr int K = 4 * IC;
  constexpr int BK = 32;
  constexpr int HS = IH * IW;
  constexpr int IH2 = IH + 2, IW2 = IW + 2;
  constexpr int OH2 = 2 * IH + 2, OW2 = 2 * IW + 2;
  constexpr int MI = WM / 16, NI = WN / 16;
  constexpr int WAVES_N = BN / WN;
  __shared__ bf16 Alds[BM * BK];
  __shared__ bf16 Blds[BN * BK];
  const int p = blockIdx.z, py = p >> 1, px = p & 1;
  const int tid = threadIdx.x;
  const int wave = tid >> 6, lane = tid & 63;
  const int wn = wave % WAVES_N, wm = wave / WAVES_N;
  const int m0 = blockIdx.x * BM, n0 = blockIdx.y * BN;

  f32x4 acc[MI][NI];
  #pragma unroll
  for (int i = 0; i < MI; ++i)
    #pragma unroll
    for (int j = 0; j < NI; ++j)
      acc[i][j] = (f32x4){0.f, 0.f, 0.f, 0.f};

  const int offy[2] = {0, py ? 1 : -1};
  const int offx[2] = {0, px ? 1 : -1};

  for (int k0 = 0; k0 < K; k0 += BK) {
    const int tap = k0 / IC;
    const int dy = tap >> 1, dx = tap & 1;
    const int ic = (k0 & (IC - 1)) + (lane & 3) * 8;
    __syncthreads();
    // stage A tile [BM][BK]
    #pragma unroll
    for (int s = 0; s < BM / 64; ++s) {
      const int si = wave + 4 * s;
      const int rl = si * 16 + (lane >> 2);
      const int m = m0 + rl;
      const int b = m / HS;
      const int rem = m % HS;
      const int iy = rem / IW + 1 + offy[dy];
      const int ix = (rem & (IW - 1)) + 1 + offx[dx];
      gload_lds16(xin + (((size_t)b * IH2 + iy) * IW2 + ix) * IC + ic,
                  Alds + si * 16 * BK);
    }
    // stage B tile [BN][BK]
    for (int s = wave; s < BN / 16; s += 4) {
      const int oc = n0 + s * 16 + (lane >> 2);
      gload_lds16(wt + ((size_t)(p * OCp + oc)) * K + k0 + (lane & 3) * 8,
                  Blds + s * 16 * BK);
    }
    __syncthreads();
    bf16x8 af[MI], bfr[NI];
    #pragma unroll
    for (int i = 0; i < MI; ++i)
      af[i] = *(const bf16x8*)(Alds + (wm * WM + i * 16 + (lane & 15)) * BK + (lane >> 4) * 8);
    #pragma unroll
    for (int j = 0; j < NI; ++j)
      bfr[j] = *(const bf16x8*)(Blds + (wn * WN + j * 16 + (lane & 15)) * BK + (lane >> 4) * 8);
    #pragma unroll
    for (int i = 0; i < MI; ++i)
      #pragma unroll
      for (int j = 0; j < NI; ++j)
        acc[i][j] = __builtin_amdgcn_mfma_f32_16x16x32_bf16(af[i], bfr[j], acc[i][j], 0, 0, 0);
  }

  // epilogue: C/D layout col = lane&15, row = (lane>>4)*4 + r
  #pragma unroll
  for (int j = 0; j < NI; ++j) {
    const int oc = n0 + wn * WN + j * 16 + (lane & 15);
    if (oc >= OCr) continue;  // padded cols (conv3)
    const float bv = bias[oc];
    #pragma unroll
    for (int i = 0; i < MI; ++i) {
      #pragma unroll
      for (int r = 0; r < 4; ++r) {
        const int ml = wm * WM + i * 16 + (lane >> 4) * 4 + r;
        const int m = m0 + ml;
        const int b = m / HS;
        const int rem = m % HS;
        const int oy = 2 * (rem / IW) + py;
        const int ox = 2 * (rem & (IW - 1)) + px;
        float v = acc[i][j][r] + bv;
        if (RELU) v = fmaxf(v, 0.f);
        if (FINAL) {
          fout[((size_t)(b * 3 + oc) * 64 + oy) * 64 + ox] = v;
        } else {
          xout[(((size_t)b * OH2 + oy + 1) * OW2 + ox + 1) * OCp + oc] = __float2bfloat16(v);
        }
      }
    }
  }
}

// ---------------- launch ----------------
extern "C" void kernel_launch(void* const* d_in, const int* in_sizes, int n_in,
                              void* d_out, int out_size, void* d_ws, size_t ws_size,
                              hipStream_t stream) {
  const float* x  = (const float*)d_in[0];
  const float* gw = (const float*)d_in[1];
  const float* gb = (const float*)d_in[2];
  const float* z  = (const float*)d_in[3];
  const float* w1 = (const float*)d_in[4];
  const float* b1 = (const float*)d_in[5];
  const float* w2 = (const float*)d_in[6];
  const float* b2 = (const float*)d_in[7];
  const float* w3 = (const float*)d_in[8];
  const float* b3 = (const float*)d_in[9];
  float* out = (float*)d_out;

  char* w = (char*)d_ws;
  // ws layout (bytes): lp 64K | x1 13107200 | x2 42467328 | x3 75759616 | wt1 524288 | wt2 262144 | wt3 32768
  float* lp  = (float*)(w);
  bf16* x1  = (bf16*)(w + 65536);
  bf16* x2  = (bf16*)(w + 13172736);
  bf16* x3  = (bf16*)(w + 55640064);
  bf16* wt1 = (bf16*)(w + 131399680);
  bf16* wt2 = (bf16*)(w + 131923968);
  bf16* wt3 = (bf16*)(w + 132186112);

  // halo zeroing (borders only)
  zero_halo<<<(512*36*16 + 255) / 256, 256, 0, stream>>>(x1, 8, 8, 128);
  zero_halo<<<(512*68*16 + 255) / 256, 256, 0, stream>>>(x2, 16, 16, 128);
  zero_halo<<<(512*132*8 + 255) / 256, 256, 0, stream>>>(x3, 32, 32, 64);

  // gating -> leaf probabilities
  gate_kernel<<<512, 64, 0, stream>>>(x, gw, gb, lp);

  // weight transforms (fp32 -> per-parity bf16)
  wprep_kernel<<<(4*128*4*128 + 255) / 256, 256, 0, stream>>>(w1, wt1, 128, 128, 128);
  wprep_kernel<<<(4*64*4*128 + 255) / 256, 256, 0, stream>>>(w2, wt2, 128, 64, 64);
  wprep_kernel<<<(4*16*4*64 + 255) / 256, 256, 0, stream>>>(w3, wt3, 64, 3, 16);

  // mixture -> x1 interior (NHWC bf16)
  mixture_kernel<<<dim3(64, 8), 256, 0, stream>>>(z, lp, x1);

  // conv1: 128->128, 8x8 -> 16x16, relu.  M/parity = 32768
  convt_mfma<128,128,128, 8, 8, 128,128, 64,64, true,false>
      <<<dim3(256, 1, 4), 256, 0, stream>>>(x1, wt1, b1, x2, nullptr);
  // conv2: 128->64, 16x16 -> 32x32, relu. M/parity = 131072
  convt_mfma<128, 64, 64,16,16, 128, 64, 64,32, true,false>
      <<<dim3(1024, 1, 4), 256, 0, stream>>>(x2, wt2, b2, x3, nullptr);
  // conv3: 64->3 (pad 16), 32x32 -> 64x64, final fp32 NCHW. M/parity = 524288
  convt_mfma< 64, 16,  3,32,32, 128, 16, 32,16, false,true>
      <<<dim3(4096, 1, 4), 256, 0, stream>>>(x3, wt3, b3, nullptr, out);
}